// Round 1
// baseline (421.232 us; speedup 1.0000x reference)
//
#include <hip/hip_runtime.h>

// GCN 3-layer: N=50000, E=1.6M, D_IN=256, H=128, D_OUT=64, fp32 in/out.
// CSR build: 4-way split-atomic degree pass (atomic return = slot), parallel
// scan with int4 sub-base table, atomic-free scatter fill.
// Per layer: split-bf16 MFMA GEMM -> CSR-SpMM over bf16 rows.
// Round 10: overlap gemm1 (MFMA-bound) with deg_slot (atomic-latency-bound).
// Round 11: attack the atomic slot pass itself (92us, all pipes <14% busy):
//   - pad each (node,class) counter to its own 64B cacheline (128 -> 8
//     atomic RMWs per line; collisions now same-address-only),
//   - 4 edges per thread with int4 dst/slot access -> 4 independent
//     in-flight atomics per thread (distinct classes, never same address),
//   - scanA compacts padded counters into dense deg4 so scanC stays cheap.

constexpr int DIN = 256;
constexpr int HID = 128;
constexpr int DOUT = 64;

typedef unsigned short ushort_t;
typedef unsigned int uint_t;
typedef __attribute__((ext_vector_type(8))) short bf16x8;
typedef __attribute__((ext_vector_type(4))) float f32x4;

__device__ inline ushort_t f2bf(float f) {
  uint_t u = __float_as_uint(f);
  u += 0x7FFF + ((u >> 16) & 1);  // RNE
  return (ushort_t)(u >> 16);
}
__device__ inline float bf2f(ushort_t b) {
  return __uint_as_float(((uint_t)b) << 16);
}

// padded counter index: (node d, class k) -> own 64B line (16 ints)
__device__ inline int cidx(int d, int k) { return ((d << 2) | k) << 4; }

// ---------- weight prep (device fn): W[K][F] fp32 -> fragment bf16 hi/lo ----------
// Layout: Bp[t = n/16][s = k/32][lane = (k/8 % 4)*16 + n%16][j = k%8]

__device__ inline void wprep_one(const float* __restrict__ W, ushort_t* __restrict__ Bhi,
                                 ushort_t* __restrict__ Blo, int K, int F, int i) {
  int k = i / F, nn = i % F;
  int t = nn >> 4, s = k >> 5, q = (k >> 3) & 3, j = k & 7;
  int lane = q * 16 + (nn & 15);
  int KS = K >> 5;
  size_t idx = (((size_t)t * KS + s) * 64 + (size_t)lane) * 8 + j;
  float w = W[i];
  ushort_t h = f2bf(w);
  float r = w - bf2f(h);
  Bhi[idx] = h;
  Blo[idx] = f2bf(r);
}

// ---------- init padded counters + wprep x3 (independent) ----------

__global__ __launch_bounds__(256) void initprep_kernel(
    int* __restrict__ cnt, int n, int iblocks,
    const float* __restrict__ W1, ushort_t* __restrict__ W1hi, ushort_t* __restrict__ W1lo,
    const float* __restrict__ W2, ushort_t* __restrict__ W2hi, ushort_t* __restrict__ W2lo,
    const float* __restrict__ W3, ushort_t* __restrict__ W3hi, ushort_t* __restrict__ W3lo) {
  if ((int)blockIdx.x < iblocks) {
    int i = blockIdx.x * 256 + threadIdx.x;
    if (i < n) {
      cnt[cidx(i, 0)] = 1;  // self-loop in class 0
      cnt[cidx(i, 1)] = 0;
      cnt[cidx(i, 2)] = 0;
      cnt[cidx(i, 3)] = 0;
    }
  } else {
    int idx = ((int)blockIdx.x - iblocks) * 256 + threadIdx.x;
    constexpr int S1 = DIN * HID;        // 32768
    constexpr int S2 = S1 + HID * HID;   // 49152
    constexpr int S3 = S2 + HID * DOUT;  // 57344
    if (idx < S1) wprep_one(W1, W1hi, W1lo, DIN, HID, idx);
    else if (idx < S2) wprep_one(W2, W2hi, W2lo, HID, HID, idx - S1);
    else if (idx < S3) wprep_one(W3, W3hi, W3lo, HID, DOUT, idx - S2);
  }
}

// ---------- split-bf16 MFMA GEMM (device fn) ----------
// 256 threads = 4 waves; 64 rows per block-id; wave w: rows +16w..+16w+15.
// acc = Ahi*Bhi + Alo*Bhi + Ahi*Blo (fp32 accum; lo*lo dropped, ~2^-18 rel).

template <int K, int F, bool SCALE>
__device__ inline void gemm_mfma_dev(const float* __restrict__ X,
    const ushort_t* __restrict__ Bhi, const ushort_t* __restrict__ Blo,
    const float* __restrict__ dinv, ushort_t* __restrict__ T, int n, int bid) {
  constexpr int NT = F / 16;   // n-tiles
  constexpr int KS = K / 32;   // k-steps
  int wave = threadIdx.x >> 6;
  int lane = threadIdx.x & 63;
  int q = lane >> 4;
  int m = lane & 15;
  int arow = bid * 64 + wave * 16 + m;
  bool valid = arow < n;
  const float* xrow = X + (size_t)arow * K;

  f32x4 acc[NT];
#pragma unroll
  for (int t = 0; t < NT; ++t) acc[t] = (f32x4){0.f, 0.f, 0.f, 0.f};

  for (int s = 0; s < KS; ++s) {
    float av[8];
    if (valid) {
      float4 u0 = *(const float4*)(xrow + s * 32 + q * 8);
      float4 u1 = *(const float4*)(xrow + s * 32 + q * 8 + 4);
      av[0] = u0.x; av[1] = u0.y; av[2] = u0.z; av[3] = u0.w;
      av[4] = u1.x; av[5] = u1.y; av[6] = u1.z; av[7] = u1.w;
    } else {
#pragma unroll
      for (int j = 0; j < 8; ++j) av[j] = 0.f;
    }
    bf16x8 ahi, alo;
#pragma unroll
    for (int j = 0; j < 8; ++j) {
      ushort_t h = f2bf(av[j]);
      ahi[j] = (short)h;
      alo[j] = (short)f2bf(av[j] - bf2f(h));
    }
#pragma unroll
    for (int t = 0; t < NT; ++t) {
      size_t boff = (((size_t)t * KS + s) * 64 + (size_t)lane) * 8;
      bf16x8 bh = *(const bf16x8*)(Bhi + boff);
      bf16x8 bl = *(const bf16x8*)(Blo + boff);
      acc[t] = __builtin_amdgcn_mfma_f32_16x16x32_bf16(ahi, bh, acc[t], 0, 0, 0);
      acc[t] = __builtin_amdgcn_mfma_f32_16x16x32_bf16(alo, bh, acc[t], 0, 0, 0);
      acc[t] = __builtin_amdgcn_mfma_f32_16x16x32_bf16(ahi, bl, acc[t], 0, 0, 0);
    }
  }

  int orow_base = bid * 64 + wave * 16 + q * 4;
#pragma unroll
  for (int r = 0; r < 4; ++r) {
    int orow = orow_base + r;
    if (orow >= n) continue;
    float sc = SCALE ? dinv[orow] : 1.0f;
    ushort_t* trow = T + (size_t)orow * F + m;
#pragma unroll
    for (int t = 0; t < NT; ++t) trow[t * 16] = f2bf(sc * acc[t][r]);
  }
}

template <int K, int F>
__global__ __launch_bounds__(256) void gemm_mfma_kernel(const float* __restrict__ X,
    const ushort_t* __restrict__ Bhi, const ushort_t* __restrict__ Blo,
    const float* __restrict__ dinv, ushort_t* __restrict__ T, int n) {
  gemm_mfma_dev<K, F, true>(X, Bhi, Blo, dinv, T, n, blockIdx.x);
}

// ---------- fused A: [gemm1 unscaled | deg_slot] ----------
// gemm1 waves use MFMA/VALU; deg_slot waves idle on atomics -> complementary.
// deg_slot: 4 edges/thread, int4 loads/stores, 4 independent padded atomics.

__global__ __launch_bounds__(256) void fusedA_kernel(
    const float* __restrict__ X, const ushort_t* __restrict__ Bhi,
    const ushort_t* __restrict__ Blo, ushort_t* __restrict__ T, int n, int gblocks,
    const int* __restrict__ dst, int* __restrict__ cnt,
    int* __restrict__ slot, int e) {
  if ((int)blockIdx.x < gblocks) {
    gemm_mfma_dev<DIN, HID, false>(X, Bhi, Blo, nullptr, T, n, blockIdx.x);
  } else {
    int i0 = ((((int)blockIdx.x - gblocks) * 256 + (int)threadIdx.x)) * 4;
    if (i0 >= e) return;
    if (i0 + 4 <= e) {
      int4 d4 = *(const int4*)(dst + i0);
      int s0 = atomicAdd(&cnt[cidx(d4.x, 0)], 1);  // >= 1 (self-loop)
      int s1 = atomicAdd(&cnt[cidx(d4.y, 1)], 1);  // >= 0
      int s2 = atomicAdd(&cnt[cidx(d4.z, 2)], 1);
      int s3 = atomicAdd(&cnt[cidx(d4.w, 3)], 1);
      int4 s4;
      s4.x = s0; s4.y = s1; s4.z = s2; s4.w = s3;
      *(int4*)(slot + i0) = s4;
    } else {
      for (int i = i0; i < e; ++i) {
        int d = dst[i];
        slot[i] = atomicAdd(&cnt[cidx(d, i & 3)], 1);
      }
    }
  }
}

// ---------- 3-phase exclusive scan of (deg-1), 1024 elems / block ----------
// scanA also compacts padded counters into dense deg4 (int4 per node).

__global__ __launch_bounds__(256) void scanA_kernel(const int* __restrict__ cnt,
    int4* __restrict__ deg4, int* __restrict__ blocksum, int n) {
  __shared__ int sums[256];
  int t = threadIdx.x;
  int base = blockIdx.x * 1024 + t * 4;
  int local = 0;
#pragma unroll
  for (int k = 0; k < 4; ++k) {
    int i = base + k;
    if (i < n) {
      int k0 = cnt[cidx(i, 0)];
      int k1 = cnt[cidx(i, 1)];
      int k2 = cnt[cidx(i, 2)];
      int k3 = cnt[cidx(i, 3)];
      int4 v;
      v.x = k0; v.y = k1; v.z = k2; v.w = k3;
      deg4[i] = v;
      local += k0 + k1 + k2 + k3 - 1;
    }
  }
  sums[t] = local;
  __syncthreads();
  for (int off = 128; off > 0; off >>= 1) {
    if (t < off) sums[t] += sums[t + off];
    __syncthreads();
  }
  if (t == 0) blocksum[blockIdx.x] = sums[0];
}

__global__ __launch_bounds__(64) void scanB_kernel(int* __restrict__ blocksum, int nb) {
  int lane = threadIdx.x;
  int carry = 0;
  for (int base = 0; base < nb; base += 64) {
    int i = base + lane;
    int orig = (i < nb) ? blocksum[i] : 0;
    int v = orig;
#pragma unroll
    for (int off = 1; off < 64; off <<= 1) {
      int u = __shfl_up(v, off, 64);
      if (lane >= off) v += u;
    }
    int total = __shfl(v, 63, 64);
    if (i < nb) blocksum[i] = carry + v - orig;  // exclusive
    carry += total;
  }
}

__global__ __launch_bounds__(256) void scanC_kernel(const int4* __restrict__ deg4,
    const int* __restrict__ blocksum, int* __restrict__ row_start, int* __restrict__ deg,
    float* __restrict__ dinv, int4* __restrict__ sub, int n) {
  __shared__ int sums[256];
  int t = threadIdx.x;
  int base = blockIdx.x * 1024 + t * 4;
  int d[4], k0[4], k1[4], k2[4];
  int local = 0;
#pragma unroll
  for (int k = 0; k < 4; ++k) {
    int i = base + k;
    if (i < n) {
      int4 v = deg4[i];
      k0[k] = v.x; k1[k] = v.y; k2[k] = v.z;
      d[k] = v.x + v.y + v.z + v.w;
      local += d[k] - 1;
    } else { d[k] = 1; k0[k] = 1; k1[k] = 0; k2[k] = 0; }
  }
  sums[t] = local;
  __syncthreads();
  for (int off = 1; off < 256; off <<= 1) {
    int v = (t >= off) ? sums[t - off] : 0;
    __syncthreads();
    sums[t] += v;
    __syncthreads();
  }
  int run = blocksum[blockIdx.x] + sums[t] - local;  // exclusive offset
#pragma unroll
  for (int k = 0; k < 4; ++k) {
    int i = base + k;
    if (i < n) {
      row_start[i] = run;
      deg[i] = d[k];
      dinv[i] = rsqrtf((float)d[k]);
      int4 sb;
      sb.x = run - 1;                  // class 0: slot >= 1 -> pos = run-1+slot
      sb.y = run + (k0[k] - 1);        // class 1: slot >= 0
      sb.z = sb.y + k1[k];             // class 2
      sb.w = sb.z + k2[k];             // class 3
      sub[i] = sb;
      run += d[k] - 1;
    }
  }
}

// ---------- fused B: [fill | scaleT] ----------
// fill: atomic-free scatter. scaleT: T[row] *= dinv[row] in place (bf16).

__global__ __launch_bounds__(256) void fusedB_kernel(
    const int* __restrict__ src, const int* __restrict__ dst,
    const int* __restrict__ slot, const int4* __restrict__ sub,
    int* __restrict__ col, int e, int fblocks,
    ushort_t* __restrict__ T, const float* __restrict__ dinv, int n) {
  if ((int)blockIdx.x < fblocks) {
    int i = blockIdx.x * 256 + threadIdx.x;
    if (i >= e) return;
    int d = dst[i];
    int k = i & 3;
    int4 sb = sub[d];
    int base = (k == 0) ? sb.x : (k == 1) ? sb.y : (k == 2) ? sb.z : sb.w;
    col[base + slot[i]] = src[i];
  } else {
    int idx = ((int)blockIdx.x - fblocks) * 256 + threadIdx.x;  // 8 bf16 each
    int total = n * (HID / 8);
    if (idx >= total) return;
    int row = idx >> 4;  // 16 chunks of 8 per row (HID=128)
    float sc = dinv[row];
    uint4* p = (uint4*)T + idx;
    uint4 v = *p;
    uint_t w[4] = {v.x, v.y, v.z, v.w};
#pragma unroll
    for (int j = 0; j < 4; ++j) {
      float lo = sc * bf2f((ushort_t)(w[j] & 0xFFFF));
      float hi = sc * bf2f((ushort_t)(w[j] >> 16));
      w[j] = (uint_t)f2bf(lo) | ((uint_t)f2bf(hi) << 16);
    }
    v.x = w[0]; v.y = w[1]; v.z = w[2]; v.w = w[3];
    *p = v;
  }
}

// ---------- CSR SpMM: out[d] = dinv[d]*(t'[d] + sum_c t'[c]) + b, opt ReLU ----------
// t' rows bf16, pre-scaled by dinv[row]. TWO destination nodes per wave (MLP).

template <int F, bool RELU>
__global__ __launch_bounds__(256) void spmm_kernel(const ushort_t* __restrict__ t,
    const int* __restrict__ row_start, const int* __restrict__ deg,
    const int* __restrict__ col, const float* __restrict__ dinv,
    const float* __restrict__ bias, float* __restrict__ out, int n) {
  int gw = (int)((blockIdx.x * 256u + threadIdx.x) >> 6);
  int lane = threadIdx.x & 63;
  int n0 = gw * 2;
  int n1 = n0 + 1;
  if (n0 >= n) return;
  bool h1 = (n1 < n);
  int rs0 = row_start[n0], e0 = deg[n0] - 1;
  int rs1 = h1 ? row_start[n1] : 0, e1 = h1 ? (deg[n1] - 1) : 0;
  float di0 = dinv[n0];
  float di1 = h1 ? dinv[n1] : 0.f;

  if constexpr (F == 128) {
    uint_t s0 = ((const uint_t*)(t + (size_t)n0 * F))[lane];
    float ax0 = bf2f((ushort_t)(s0 & 0xFFFF)), ay0 = bf2f((ushort_t)(s0 >> 16));
    float ax1 = 0.f, ay1 = 0.f;
    if (h1) {
      uint_t s1 = ((const uint_t*)(t + (size_t)n1 * F))[lane];
      ax1 = bf2f((ushort_t)(s1 & 0xFFFF)); ay1 = bf2f((ushort_t)(s1 >> 16));
    }
    int p0 = rs0, q0 = rs0 + e0;
    int p1 = rs1, q1 = rs1 + e1;
    while (p0 + 4 <= q0 && p1 + 4 <= q1) {
      int c[8];
      uint_t v[8];
#pragma unroll
      for (int j = 0; j < 4; ++j) { c[j] = col[p0 + j]; c[4 + j] = col[p1 + j]; }
#pragma unroll
      for (int j = 0; j < 8; ++j) v[j] = ((const uint_t*)(t + (size_t)c[j] * F))[lane];
#pragma unroll
      for (int j = 0; j < 4; ++j) {
        ax0 += bf2f((ushort_t)(v[j] & 0xFFFF));
        ay0 += bf2f((ushort_t)(v[j] >> 16));
        ax1 += bf2f((ushort_t)(v[4 + j] & 0xFFFF));
        ay1 += bf2f((ushort_t)(v[4 + j] >> 16));
      }
      p0 += 4; p1 += 4;
    }
    for (; p0 + 4 <= q0; p0 += 4) {
      int c[4]; uint_t v[4];
#pragma unroll
      for (int j = 0; j < 4; ++j) c[j] = col[p0 + j];
#pragma unroll
      for (int j = 0; j < 4; ++j) v[j] = ((const uint_t*)(t + (size_t)c[j] * F))[lane];
#pragma unroll
      for (int j = 0; j < 4; ++j) {
        ax0 += bf2f((ushort_t)(v[j] & 0xFFFF)); ay0 += bf2f((ushort_t)(v[j] >> 16));
      }
    }
    for (; p0 < q0; ++p0) {
      uint_t v = ((const uint_t*)(t + (size_t)col[p0] * F))[lane];
      ax0 += bf2f((ushort_t)(v & 0xFFFF)); ay0 += bf2f((ushort_t)(v >> 16));
    }
    for (; p1 + 4 <= q1; p1 += 4) {
      int c[4]; uint_t v[4];
#pragma unroll
      for (int j = 0; j < 4; ++j) c[j] = col[p1 + j];
#pragma unroll
      for (int j = 0; j < 4; ++j) v[j] = ((const uint_t*)(t + (size_t)c[j] * F))[lane];
#pragma unroll
      for (int j = 0; j < 4; ++j) {
        ax1 += bf2f((ushort_t)(v[j] & 0xFFFF)); ay1 += bf2f((ushort_t)(v[j] >> 16));
      }
    }
    for (; p1 < q1; ++p1) {
      uint_t v = ((const uint_t*)(t + (size_t)col[p1] * F))[lane];
      ax1 += bf2f((ushort_t)(v & 0xFFFF)); ay1 += bf2f((ushort_t)(v >> 16));
    }
    float bx = bias[2 * lane], by = bias[2 * lane + 1];
    ax0 = fmaf(di0, ax0, bx); ay0 = fmaf(di0, ay0, by);
    if constexpr (RELU) { ax0 = fmaxf(ax0, 0.f); ay0 = fmaxf(ay0, 0.f); }
    float2 o0; o0.x = ax0; o0.y = ay0;
    ((float2*)(out + (size_t)n0 * F))[lane] = o0;
    if (h1) {
      ax1 = fmaf(di1, ax1, bx); ay1 = fmaf(di1, ay1, by);
      if constexpr (RELU) { ax1 = fmaxf(ax1, 0.f); ay1 = fmaxf(ay1, 0.f); }
      float2 o1; o1.x = ax1; o1.y = ay1;
      ((float2*)(out + (size_t)n1 * F))[lane] = o1;
    }
  } else {  // F == 64: one bf16 per lane
    float a0 = bf2f(t[(size_t)n0 * F + lane]);
    float a1 = h1 ? bf2f(t[(size_t)n1 * F + lane]) : 0.f;
    int p0 = rs0, q0 = rs0 + e0;
    int p1 = rs1, q1 = rs1 + e1;
    while (p0 + 4 <= q0 && p1 + 4 <= q1) {
      int c[8];
      ushort_t v[8];
#pragma unroll
      for (int j = 0; j < 4; ++j) { c[j] = col[p0 + j]; c[4 + j] = col[p1 + j]; }
#pragma unroll
      for (int j = 0; j < 8; ++j) v[j] = t[(size_t)c[j] * F + lane];
#pragma unroll
      for (int j = 0; j < 4; ++j) { a0 += bf2f(v[j]); a1 += bf2f(v[4 + j]); }
      p0 += 4; p1 += 4;
    }
    for (; p0 + 4 <= q0; p0 += 4) {
      int c[4]; ushort_t v[4];
#pragma unroll
      for (int j = 0; j < 4; ++j) c[j] = col[p0 + j];
#pragma unroll
      for (int j = 0; j < 4; ++j) v[j] = t[(size_t)c[j] * F + lane];
#pragma unroll
      for (int j = 0; j < 4; ++j) a0 += bf2f(v[j]);
    }
    for (; p0 < q0; ++p0) a0 += bf2f(t[(size_t)col[p0] * F + lane]);
    for (; p1 + 4 <= q1; p1 += 4) {
      int c[4]; ushort_t v[4];
#pragma unroll
      for (int j = 0; j < 4; ++j) c[j] = col[p1 + j];
#pragma unroll
      for (int j = 0; j < 4; ++j) v[j] = t[(size_t)c[j] * F + lane];
#pragma unroll
      for (int j = 0; j < 4; ++j) a1 += bf2f(v[j]);
    }
    for (; p1 < q1; ++p1) a1 += bf2f(t[(size_t)col[p1] * F + lane]);
    float b = bias[lane];
    a0 = fmaf(di0, a0, b);
    if constexpr (RELU) a0 = fmaxf(a0, 0.f);
    out[(size_t)n0 * F + lane] = a0;
    if (h1) {
      a1 = fmaf(di1, a1, b);
      if constexpr (RELU) a1 = fmaxf(a1, 0.f);
      out[(size_t)n1 * F + lane] = a1;
    }
  }
}

// ---------- launch ----------

extern "C" void kernel_launch(void* const* d_in, const int* in_sizes, int n_in,
                              void* d_out, int out_size, void* d_ws, size_t ws_size,
                              hipStream_t stream) {
  const float* x  = (const float*)d_in[0];
  const float* W1 = (const float*)d_in[1];
  const float* b1 = (const float*)d_in[2];
  const float* W2 = (const float*)d_in[3];
  const float* b2 = (const float*)d_in[4];
  const float* W3 = (const float*)d_in[5];
  const float* b3 = (const float*)d_in[6];
  const int* ei   = (const int*)d_in[7];  // harness delivers integers as int32

  int n = in_sizes[0] / DIN;
  int e = in_sizes[7] / 2;
  const int* src = ei;
  const int* dst = ei + e;

  char* ws = (char*)d_ws;
  size_t off = 0;
  auto alloc = [&](size_t bytes) -> void* {
    off = (off + 255) & ~(size_t)255;
    void* p = ws + off;
    off += bytes;
    return p;
  };
  int nscan = (n + 1023) / 1024;
  int*      cnt       = (int*)alloc((size_t)n * 4 * 64);   // padded: 64B/counter
  int4*     deg4      = (int4*)alloc((size_t)n * 16);      // compacted counters
  int*      deg       = (int*)alloc((size_t)n * 4);
  float*    dinv      = (float*)alloc((size_t)n * 4);
  int*      row_start = (int*)alloc((size_t)n * 4);
  int4*     sub       = (int4*)alloc((size_t)n * 16);
  int*      blocksum  = (int*)alloc((size_t)nscan * 4);
  int*      slot      = (int*)alloc((size_t)e * 4);
  int*      col       = (int*)alloc((size_t)e * 4);
  ushort_t* T         = (ushort_t*)alloc((size_t)n * HID * 2);  // bf16 GEMM out
  float*    Hf        = (float*)alloc((size_t)n * HID * 4);     // fp32 SpMM out
  ushort_t* W1hi      = (ushort_t*)alloc((size_t)DIN * HID * 2);
  ushort_t* W1lo      = (ushort_t*)alloc((size_t)DIN * HID * 2);
  ushort_t* W2hi      = (ushort_t*)alloc((size_t)HID * HID * 2);
  ushort_t* W2lo      = (ushort_t*)alloc((size_t)HID * HID * 2);
  ushort_t* W3hi      = (ushort_t*)alloc((size_t)HID * DOUT * 2);
  ushort_t* W3lo      = (ushort_t*)alloc((size_t)HID * DOUT * 2);
  (void)ws_size;

  int nb256 = (n + 255) / 256;
  int eb256 = (e + 255) / 256;
  int db1024 = (e + 1023) / 1024;           // deg blocks: 4 edges/thread
  int gemm_blocks = (n + 63) / 64;
  int nwaves = (n + 1) / 2;                 // 2 nodes per wave
  int spmm_blocks = (nwaves + 3) / 4;       // 4 waves per block
  constexpr int WPREP_TOTAL = DIN * HID + HID * HID + HID * DOUT;  // 57344
  int wblocks = (WPREP_TOTAL + 255) / 256;  // 224
  int sblocks = (n * (HID / 8) + 255) / 256;  // scaleT blocks (8 bf16/thread)

  initprep_kernel<<<nb256 + wblocks, 256, 0, stream>>>(
      cnt, n, nb256,
      W1, W1hi, W1lo, W2, W2hi, W2lo, W3, W3hi, W3lo);
  fusedA_kernel<<<gemm_blocks + db1024, 256, 0, stream>>>(
      x, W1hi, W1lo, T, n, gemm_blocks,
      dst, cnt, slot, e);
  scanA_kernel<<<nscan, 256, 0, stream>>>(cnt, deg4, blocksum, n);
  scanB_kernel<<<1, 64, 0, stream>>>(blocksum, nscan);
  scanC_kernel<<<nscan, 256, 0, stream>>>(deg4, blocksum, row_start, deg, dinv, sub, n);
  fusedB_kernel<<<eb256 + sblocks, 256, 0, stream>>>(
      src, dst, slot, sub, col, e, eb256, T, dinv, n);

  spmm_kernel<HID, true><<<spmm_blocks, 256, 0, stream>>>(T, row_start, deg, col, dinv, b1, Hf, n);
  gemm_mfma_kernel<HID, HID><<<gemm_blocks, 256, 0, stream>>>(Hf, W2hi, W2lo, dinv, T, n);
  spmm_kernel<HID, true><<<spmm_blocks, 256, 0, stream>>>(T, row_start, deg, col, dinv, b2, Hf, n);
  gemm_mfma_kernel<HID, DOUT><<<gemm_blocks, 256, 0, stream>>>(Hf, W3hi, W3lo, dinv, T, n);
  spmm_kernel<DOUT, false><<<spmm_blocks, 256, 0, stream>>>(T, row_start, deg, col, dinv, b3, (float*)d_out, n);
}

// Round 2
// 354.484 us; speedup vs baseline: 1.1883x; 1.1883x over previous
//
#include <hip/hip_runtime.h>

// GCN 3-layer: N=50000, E=1.6M, D_IN=256, H=128, D_OUT=64, fp32 in/out.
// Round 12: atomic-wall workaround. R11 falsified line-collision + MLP theories
// (padding & 4x MLP made it worse) -> returning global atomics are throughput-
// limited at the memory-side coherence point (~17G/s; WRITE_SIZE shows ~32B/op
// writethrough). So reduce global atomic COUNT 10x via 2-level bucketed
// counting sort (bucket = dst>>6, 64 nodes/bucket):
//   bin:    per-block LDS histogram + 1 returning global atomic per
//           (block,bucket) = 153K atomics (was 1.6M).
//   scan:   782-entry bucket scan (one block). Global node scan is GONE --
//           buckets are contiguous node ranges so CSR offsets are local.
//   fusedA2:[gemm1 unscaled | scatter]: LDS-atomic re-rank, write packed
//           (dst<<16|src) u32 into bucket region. Zero global atomics.
//   csr:    per-bucket LDS count -> wave scan -> deg/dinv/row_start/col.
//   scaleT eliminated: layer-1 SpMM gathers dinv[c] per edge (GD variant).
// Requires n <= 65536 (16-bit packing; harness n = 50000).

constexpr int DIN = 256;
constexpr int HID = 128;
constexpr int DOUT = 64;
constexpr int MAXB = 1024;   // max buckets (n <= 65536)
constexpr int BSH = 6;       // 64 nodes per bucket
constexpr int EPB = 8192;    // edges per bin/scatter block

typedef unsigned short ushort_t;
typedef unsigned int uint_t;
typedef __attribute__((ext_vector_type(8))) short bf16x8;
typedef __attribute__((ext_vector_type(4))) float f32x4;

__device__ inline ushort_t f2bf(float f) {
  uint_t u = __float_as_uint(f);
  u += 0x7FFF + ((u >> 16) & 1);  // RNE
  return (ushort_t)(u >> 16);
}
__device__ inline float bf2f(ushort_t b) {
  return __uint_as_float(((uint_t)b) << 16);
}

// ---------- weight prep (device fn): W[K][F] fp32 -> fragment bf16 hi/lo ----------
// Layout: Bp[t = n/16][s = k/32][lane = (k/8 % 4)*16 + n%16][j = k%8]

__device__ inline void wprep_one(const float* __restrict__ W, ushort_t* __restrict__ Bhi,
                                 ushort_t* __restrict__ Blo, int K, int F, int i) {
  int k = i / F, nn = i % F;
  int t = nn >> 4, s = k >> 5, q = (k >> 3) & 3, j = k & 7;
  int lane = q * 16 + (nn & 15);
  int KS = K >> 5;
  size_t idx = (((size_t)t * KS + s) * 64 + (size_t)lane) * 8 + j;
  float w = W[i];
  ushort_t h = f2bf(w);
  float r = w - bf2f(h);
  Bhi[idx] = h;
  Blo[idx] = f2bf(r);
}

// ---------- init: zero bucket_total + wprep x3 ----------

__global__ __launch_bounds__(256) void initprep_kernel(
    int* __restrict__ bucket_total, int iblocks,
    const float* __restrict__ W1, ushort_t* __restrict__ W1hi, ushort_t* __restrict__ W1lo,
    const float* __restrict__ W2, ushort_t* __restrict__ W2hi, ushort_t* __restrict__ W2lo,
    const float* __restrict__ W3, ushort_t* __restrict__ W3hi, ushort_t* __restrict__ W3lo) {
  if ((int)blockIdx.x < iblocks) {
    int i = blockIdx.x * 256 + threadIdx.x;
    if (i < MAXB) bucket_total[i] = 0;
  } else {
    int idx = ((int)blockIdx.x - iblocks) * 256 + threadIdx.x;
    constexpr int S1 = DIN * HID;        // 32768
    constexpr int S2 = S1 + HID * HID;   // 49152
    constexpr int S3 = S2 + HID * DOUT;  // 57344
    if (idx < S1) wprep_one(W1, W1hi, W1lo, DIN, HID, idx);
    else if (idx < S2) wprep_one(W2, W2hi, W2lo, HID, HID, idx - S1);
    else if (idx < S3) wprep_one(W3, W3hi, W3lo, HID, DOUT, idx - S2);
  }
}

// ---------- bin pass: per-block LDS histogram over buckets ----------
// One returning global atomic per (block,bucket) -> block's base within bucket.

__global__ __launch_bounds__(256) void bin_kernel(const int* __restrict__ dst, int e,
    int nbuckets, int* __restrict__ bucket_total, int* __restrict__ block_base) {
  __shared__ int h[MAXB];
  int tid = threadIdx.x;
  for (int i = tid; i < nbuckets; i += 256) h[i] = 0;
  __syncthreads();
  int base = blockIdx.x * EPB;
  int end = min(base + EPB, e);
  for (int i = base + tid; i < end; i += 256) atomicAdd(&h[dst[i] >> BSH], 1);
  __syncthreads();
  for (int i = tid; i < nbuckets; i += 256) {
    int v = h[i];
    if (v) block_base[(size_t)blockIdx.x * nbuckets + i] = atomicAdd(&bucket_total[i], v);
  }
}

// ---------- bucket scan: exclusive scan of bucket_total (+ sentinel) ----------

__global__ __launch_bounds__(256) void scan_buckets_kernel(const int* __restrict__ total,
    int* __restrict__ base, int nb) {
  __shared__ int sums[256];
  int t = threadIdx.x;
  int a[4];
  int ls = 0;
#pragma unroll
  for (int k = 0; k < 4; ++k) {
    int idx = t * 4 + k;
    a[k] = (idx < nb) ? total[idx] : 0;
    ls += a[k];
  }
  sums[t] = ls;
  __syncthreads();
  for (int off = 1; off < 256; off <<= 1) {
    int u = (t >= off) ? sums[t - off] : 0;
    __syncthreads();
    sums[t] += u;
    __syncthreads();
  }
  int run = sums[t] - ls;  // exclusive
#pragma unroll
  for (int k = 0; k < 4; ++k) {
    int idx = t * 4 + k;
    if (idx < nb) base[idx] = run;
    run += a[k];
  }
  if (t == 255) base[nb] = sums[255];  // sentinel = e
}

// ---------- split-bf16 MFMA GEMM (device fn) ----------
// 256 threads = 4 waves; 64 rows per block-id; wave w: rows +16w..+16w+15.
// acc = Ahi*Bhi + Alo*Bhi + Ahi*Blo (fp32 accum; lo*lo dropped, ~2^-18 rel).

template <int K, int F, bool SCALE>
__device__ inline void gemm_mfma_dev(const float* __restrict__ X,
    const ushort_t* __restrict__ Bhi, const ushort_t* __restrict__ Blo,
    const float* __restrict__ dinv, ushort_t* __restrict__ T, int n, int bid) {
  constexpr int NT = F / 16;   // n-tiles
  constexpr int KS = K / 32;   // k-steps
  int wave = threadIdx.x >> 6;
  int lane = threadIdx.x & 63;
  int q = lane >> 4;
  int m = lane & 15;
  int arow = bid * 64 + wave * 16 + m;
  bool valid = arow < n;
  const float* xrow = X + (size_t)arow * K;

  f32x4 acc[NT];
#pragma unroll
  for (int t = 0; t < NT; ++t) acc[t] = (f32x4){0.f, 0.f, 0.f, 0.f};

  for (int s = 0; s < KS; ++s) {
    float av[8];
    if (valid) {
      float4 u0 = *(const float4*)(xrow + s * 32 + q * 8);
      float4 u1 = *(const float4*)(xrow + s * 32 + q * 8 + 4);
      av[0] = u0.x; av[1] = u0.y; av[2] = u0.z; av[3] = u0.w;
      av[4] = u1.x; av[5] = u1.y; av[6] = u1.z; av[7] = u1.w;
    } else {
#pragma unroll
      for (int j = 0; j < 8; ++j) av[j] = 0.f;
    }
    bf16x8 ahi, alo;
#pragma unroll
    for (int j = 0; j < 8; ++j) {
      ushort_t h = f2bf(av[j]);
      ahi[j] = (short)h;
      alo[j] = (short)f2bf(av[j] - bf2f(h));
    }
#pragma unroll
    for (int t = 0; t < NT; ++t) {
      size_t boff = (((size_t)t * KS + s) * 64 + (size_t)lane) * 8;
      bf16x8 bh = *(const bf16x8*)(Bhi + boff);
      bf16x8 bl = *(const bf16x8*)(Blo + boff);
      acc[t] = __builtin_amdgcn_mfma_f32_16x16x32_bf16(ahi, bh, acc[t], 0, 0, 0);
      acc[t] = __builtin_amdgcn_mfma_f32_16x16x32_bf16(alo, bh, acc[t], 0, 0, 0);
      acc[t] = __builtin_amdgcn_mfma_f32_16x16x32_bf16(ahi, bl, acc[t], 0, 0, 0);
    }
  }

  int orow_base = bid * 64 + wave * 16 + q * 4;
#pragma unroll
  for (int r = 0; r < 4; ++r) {
    int orow = orow_base + r;
    if (orow >= n) continue;
    float sc = SCALE ? dinv[orow] : 1.0f;
    ushort_t* trow = T + (size_t)orow * F + m;
#pragma unroll
    for (int t = 0; t < NT; ++t) trow[t * 16] = f2bf(sc * acc[t][r]);
  }
}

template <int K, int F>
__global__ __launch_bounds__(256) void gemm_mfma_kernel(const float* __restrict__ X,
    const ushort_t* __restrict__ Bhi, const ushort_t* __restrict__ Blo,
    const float* __restrict__ dinv, ushort_t* __restrict__ T, int n) {
  gemm_mfma_dev<K, F, true>(X, Bhi, Blo, dinv, T, n, blockIdx.x);
}

// ---------- fused A2: [gemm1 unscaled | scatter into buckets] ----------
// scatter: LDS re-histogram gives rank within (block,bucket); position =
// bucket_base[b] + block_base[blk][b] + rank. Zero global atomics.

__global__ __launch_bounds__(256) void fusedA2_kernel(
    const float* __restrict__ X, const ushort_t* __restrict__ Bhi,
    const ushort_t* __restrict__ Blo, ushort_t* __restrict__ T, int n, int gblocks,
    const int* __restrict__ src, const int* __restrict__ dst,
    const int* __restrict__ bucket_base, const int* __restrict__ block_base,
    uint_t* __restrict__ binned, int e, int nbuckets) {
  if ((int)blockIdx.x < gblocks) {
    gemm_mfma_dev<DIN, HID, false>(X, Bhi, Blo, nullptr, T, n, blockIdx.x);
  } else {
    __shared__ int rkh[MAXB];
    __shared__ int cbase[MAXB];
    int tid = threadIdx.x;
    int blk = (int)blockIdx.x - gblocks;
    for (int i = tid; i < nbuckets; i += 256) {
      rkh[i] = 0;
      cbase[i] = bucket_base[i] + block_base[(size_t)blk * nbuckets + i];
    }
    __syncthreads();
    int base = blk * EPB;
    int end = min(base + EPB, e);
    for (int i = base + tid; i < end; i += 256) {
      int d = dst[i];
      int s = src[i];
      int b = d >> BSH;
      int r = atomicAdd(&rkh[b], 1);
      binned[cbase[b] + r] = ((uint_t)d << 16) | (uint_t)s;
    }
  }
}

// ---------- per-bucket CSR build: deg, dinv, row_start, col ----------
// Bucket = contiguous node range -> offsets are bucket-local; no global scan.

__global__ __launch_bounds__(256) void csr_kernel(const uint_t* __restrict__ binned,
    const int* __restrict__ bucket_base, int n, int* __restrict__ row_start,
    int* __restrict__ deg, float* __restrict__ dinv, int* __restrict__ col) {
  __shared__ int cnt[64];
  __shared__ int rk[64];
  __shared__ int rs[64];
  __shared__ int ebs[2];
  int tid = threadIdx.x;
  int b = blockIdx.x;
  int node0 = b << BSH;
  if (tid < 64) { cnt[tid] = 0; rk[tid] = 0; }
  if (tid == 0) { ebs[0] = bucket_base[b]; ebs[1] = bucket_base[b + 1]; }
  __syncthreads();
  int ebase = ebs[0];
  int esz = ebs[1] - ebase;
  for (int i = tid; i < esz; i += 256)
    atomicAdd(&cnt[(int)(binned[ebase + i] >> 16) - node0], 1);
  __syncthreads();
  if (tid < 64) {
    int v = cnt[tid];
    int inc = v;
#pragma unroll
    for (int off = 1; off < 64; off <<= 1) {
      int u = __shfl_up(inc, off, 64);
      if (tid >= off) inc += u;
    }
    rs[tid] = inc - v;  // exclusive within bucket
    int node = node0 + tid;
    if (node < n) {
      deg[node] = v + 1;                      // + self-loop
      dinv[node] = rsqrtf((float)(v + 1));
      row_start[node] = ebase + (inc - v);
    }
  }
  __syncthreads();
  for (int i = tid; i < esz; i += 256) {
    uint_t p = binned[ebase + i];
    int l = (int)(p >> 16) - node0;
    int r = atomicAdd(&rk[l], 1);
    col[ebase + rs[l] + r] = (int)(p & 0xFFFFu);
  }
}

// ---------- CSR SpMM: out[d] = dinv[d]*(T'[d] + sum_c T'[c]) + b, opt ReLU ----------
// GD=false: t rows pre-scaled by dinv[row] (gemm applied it).
// GD=true (layer 1): t rows UNSCALED; gather dinv[c] per edge.
// TWO destination nodes per wave (MLP).

template <int F, bool RELU, bool GD>
__global__ __launch_bounds__(256) void spmm_kernel(const ushort_t* __restrict__ t,
    const int* __restrict__ row_start, const int* __restrict__ deg,
    const int* __restrict__ col, const float* __restrict__ dinv,
    const float* __restrict__ bias, float* __restrict__ out, int n) {
  int gw = (int)((blockIdx.x * 256u + threadIdx.x) >> 6);
  int lane = threadIdx.x & 63;
  int n0 = gw * 2;
  int n1 = n0 + 1;
  if (n0 >= n) return;
  bool h1 = (n1 < n);
  int rs0 = row_start[n0], e0 = deg[n0] - 1;
  int rs1 = h1 ? row_start[n1] : 0, e1 = h1 ? (deg[n1] - 1) : 0;
  float di0 = dinv[n0];
  float di1 = h1 ? dinv[n1] : 0.f;

  if constexpr (F == 128) {
    uint_t s0 = ((const uint_t*)(t + (size_t)n0 * F))[lane];
    float ax0 = bf2f((ushort_t)(s0 & 0xFFFF)), ay0 = bf2f((ushort_t)(s0 >> 16));
    if constexpr (GD) { ax0 *= di0; ay0 *= di0; }  // self term: dinv[n0]*h[n0]
    float ax1 = 0.f, ay1 = 0.f;
    if (h1) {
      uint_t s1 = ((const uint_t*)(t + (size_t)n1 * F))[lane];
      ax1 = bf2f((ushort_t)(s1 & 0xFFFF)); ay1 = bf2f((ushort_t)(s1 >> 16));
      if constexpr (GD) { ax1 *= di1; ay1 *= di1; }
    }
    int p0 = rs0, q0 = rs0 + e0;
    int p1 = rs1, q1 = rs1 + e1;
    while (p0 + 4 <= q0 && p1 + 4 <= q1) {
      int c[8];
      uint_t v[8];
      float dc[8];
#pragma unroll
      for (int j = 0; j < 4; ++j) { c[j] = col[p0 + j]; c[4 + j] = col[p1 + j]; }
#pragma unroll
      for (int j = 0; j < 8; ++j) {
        v[j] = ((const uint_t*)(t + (size_t)c[j] * F))[lane];
        if constexpr (GD) dc[j] = dinv[c[j]];
      }
#pragma unroll
      for (int j = 0; j < 4; ++j) {
        if constexpr (GD) {
          ax0 = fmaf(dc[j], bf2f((ushort_t)(v[j] & 0xFFFF)), ax0);
          ay0 = fmaf(dc[j], bf2f((ushort_t)(v[j] >> 16)), ay0);
          ax1 = fmaf(dc[4 + j], bf2f((ushort_t)(v[4 + j] & 0xFFFF)), ax1);
          ay1 = fmaf(dc[4 + j], bf2f((ushort_t)(v[4 + j] >> 16)), ay1);
        } else {
          ax0 += bf2f((ushort_t)(v[j] & 0xFFFF));
          ay0 += bf2f((ushort_t)(v[j] >> 16));
          ax1 += bf2f((ushort_t)(v[4 + j] & 0xFFFF));
          ay1 += bf2f((ushort_t)(v[4 + j] >> 16));
        }
      }
      p0 += 4; p1 += 4;
    }
    for (; p0 + 4 <= q0; p0 += 4) {
      int c[4]; uint_t v[4]; float dc[4];
#pragma unroll
      for (int j = 0; j < 4; ++j) c[j] = col[p0 + j];
#pragma unroll
      for (int j = 0; j < 4; ++j) {
        v[j] = ((const uint_t*)(t + (size_t)c[j] * F))[lane];
        if constexpr (GD) dc[j] = dinv[c[j]];
      }
#pragma unroll
      for (int j = 0; j < 4; ++j) {
        if constexpr (GD) {
          ax0 = fmaf(dc[j], bf2f((ushort_t)(v[j] & 0xFFFF)), ax0);
          ay0 = fmaf(dc[j], bf2f((ushort_t)(v[j] >> 16)), ay0);
        } else {
          ax0 += bf2f((ushort_t)(v[j] & 0xFFFF)); ay0 += bf2f((ushort_t)(v[j] >> 16));
        }
      }
    }
    for (; p0 < q0; ++p0) {
      int c = col[p0];
      uint_t v = ((const uint_t*)(t + (size_t)c * F))[lane];
      float d = GD ? dinv[c] : 1.f;
      if constexpr (GD) {
        ax0 = fmaf(d, bf2f((ushort_t)(v & 0xFFFF)), ax0);
        ay0 = fmaf(d, bf2f((ushort_t)(v >> 16)), ay0);
      } else {
        ax0 += bf2f((ushort_t)(v & 0xFFFF)); ay0 += bf2f((ushort_t)(v >> 16));
      }
    }
    for (; p1 + 4 <= q1; p1 += 4) {
      int c[4]; uint_t v[4]; float dc[4];
#pragma unroll
      for (int j = 0; j < 4; ++j) c[j] = col[p1 + j];
#pragma unroll
      for (int j = 0; j < 4; ++j) {
        v[j] = ((const uint_t*)(t + (size_t)c[j] * F))[lane];
        if constexpr (GD) dc[j] = dinv[c[j]];
      }
#pragma unroll
      for (int j = 0; j < 4; ++j) {
        if constexpr (GD) {
          ax1 = fmaf(dc[j], bf2f((ushort_t)(v[j] & 0xFFFF)), ax1);
          ay1 = fmaf(dc[j], bf2f((ushort_t)(v[j] >> 16)), ay1);
        } else {
          ax1 += bf2f((ushort_t)(v[j] & 0xFFFF)); ay1 += bf2f((ushort_t)(v[j] >> 16));
        }
      }
    }
    for (; p1 < q1; ++p1) {
      int c = col[p1];
      uint_t v = ((const uint_t*)(t + (size_t)c * F))[lane];
      float d = GD ? dinv[c] : 1.f;
      if constexpr (GD) {
        ax1 = fmaf(d, bf2f((ushort_t)(v & 0xFFFF)), ax1);
        ay1 = fmaf(d, bf2f((ushort_t)(v >> 16)), ay1);
      } else {
        ax1 += bf2f((ushort_t)(v & 0xFFFF)); ay1 += bf2f((ushort_t)(v >> 16));
      }
    }
    float bx = bias[2 * lane], by = bias[2 * lane + 1];
    ax0 = fmaf(di0, ax0, bx); ay0 = fmaf(di0, ay0, by);
    if constexpr (RELU) { ax0 = fmaxf(ax0, 0.f); ay0 = fmaxf(ay0, 0.f); }
    float2 o0; o0.x = ax0; o0.y = ay0;
    ((float2*)(out + (size_t)n0 * F))[lane] = o0;
    if (h1) {
      ax1 = fmaf(di1, ax1, bx); ay1 = fmaf(di1, ay1, by);
      if constexpr (RELU) { ax1 = fmaxf(ax1, 0.f); ay1 = fmaxf(ay1, 0.f); }
      float2 o1; o1.x = ax1; o1.y = ay1;
      ((float2*)(out + (size_t)n1 * F))[lane] = o1;
    }
  } else {  // F == 64: one bf16 per lane (GD not used here)
    float a0 = bf2f(t[(size_t)n0 * F + lane]);
    float a1 = h1 ? bf2f(t[(size_t)n1 * F + lane]) : 0.f;
    int p0 = rs0, q0 = rs0 + e0;
    int p1 = rs1, q1 = rs1 + e1;
    while (p0 + 4 <= q0 && p1 + 4 <= q1) {
      int c[8];
      ushort_t v[8];
#pragma unroll
      for (int j = 0; j < 4; ++j) { c[j] = col[p0 + j]; c[4 + j] = col[p1 + j]; }
#pragma unroll
      for (int j = 0; j < 8; ++j) v[j] = t[(size_t)c[j] * F + lane];
#pragma unroll
      for (int j = 0; j < 4; ++j) { a0 += bf2f(v[j]); a1 += bf2f(v[4 + j]); }
      p0 += 4; p1 += 4;
    }
    for (; p0 + 4 <= q0; p0 += 4) {
      int c[4]; ushort_t v[4];
#pragma unroll
      for (int j = 0; j < 4; ++j) c[j] = col[p0 + j];
#pragma unroll
      for (int j = 0; j < 4; ++j) v[j] = t[(size_t)c[j] * F + lane];
#pragma unroll
      for (int j = 0; j < 4; ++j) a0 += bf2f(v[j]);
    }
    for (; p0 < q0; ++p0) a0 += bf2f(t[(size_t)col[p0] * F + lane]);
    for (; p1 + 4 <= q1; p1 += 4) {
      int c[4]; ushort_t v[4];
#pragma unroll
      for (int j = 0; j < 4; ++j) c[j] = col[p1 + j];
#pragma unroll
      for (int j = 0; j < 4; ++j) v[j] = t[(size_t)c[j] * F + lane];
#pragma unroll
      for (int j = 0; j < 4; ++j) a1 += bf2f(v[j]);
    }
    for (; p1 < q1; ++p1) a1 += bf2f(t[(size_t)col[p1] * F + lane]);
    float b = bias[lane];
    a0 = fmaf(di0, a0, b);
    if constexpr (RELU) a0 = fmaxf(a0, 0.f);
    out[(size_t)n0 * F + lane] = a0;
    if (h1) {
      a1 = fmaf(di1, a1, b);
      if constexpr (RELU) a1 = fmaxf(a1, 0.f);
      out[(size_t)n1 * F + lane] = a1;
    }
  }
}

// ---------- launch ----------

extern "C" void kernel_launch(void* const* d_in, const int* in_sizes, int n_in,
                              void* d_out, int out_size, void* d_ws, size_t ws_size,
                              hipStream_t stream) {
  const float* x  = (const float*)d_in[0];
  const float* W1 = (const float*)d_in[1];
  const float* b1 = (const float*)d_in[2];
  const float* W2 = (const float*)d_in[3];
  const float* b2 = (const float*)d_in[4];
  const float* W3 = (const float*)d_in[5];
  const float* b3 = (const float*)d_in[6];
  const int* ei   = (const int*)d_in[7];  // harness delivers integers as int32

  int n = in_sizes[0] / DIN;
  int e = in_sizes[7] / 2;
  const int* src = ei;
  const int* dst = ei + e;

  char* ws = (char*)d_ws;
  size_t off = 0;
  auto alloc = [&](size_t bytes) -> void* {
    off = (off + 255) & ~(size_t)255;
    void* p = ws + off;
    off += bytes;
    return p;
  };
  int nbuckets = (n + 63) >> BSH;          // <= MAXB for n <= 65536
  int nbin = (e + EPB - 1) / EPB;

  int*      bucket_total = (int*)alloc((size_t)MAXB * 4);
  int*      bucket_base  = (int*)alloc((size_t)(MAXB + 1) * 4);
  int*      block_base   = (int*)alloc((size_t)nbin * nbuckets * 4);
  uint_t*   binned       = (uint_t*)alloc((size_t)e * 4);
  int*      deg          = (int*)alloc((size_t)n * 4);
  float*    dinv         = (float*)alloc((size_t)n * 4);
  int*      row_start    = (int*)alloc((size_t)n * 4);
  int*      col          = (int*)alloc((size_t)e * 4);
  ushort_t* T            = (ushort_t*)alloc((size_t)n * HID * 2);  // bf16 GEMM out
  float*    Hf           = (float*)alloc((size_t)n * HID * 4);     // fp32 SpMM out
  ushort_t* W1hi         = (ushort_t*)alloc((size_t)DIN * HID * 2);
  ushort_t* W1lo         = (ushort_t*)alloc((size_t)DIN * HID * 2);
  ushort_t* W2hi         = (ushort_t*)alloc((size_t)HID * HID * 2);
  ushort_t* W2lo         = (ushort_t*)alloc((size_t)HID * HID * 2);
  ushort_t* W3hi         = (ushort_t*)alloc((size_t)HID * DOUT * 2);
  ushort_t* W3lo         = (ushort_t*)alloc((size_t)HID * DOUT * 2);
  (void)ws_size;

  int gemm_blocks = (n + 63) / 64;
  int nwaves = (n + 1) / 2;                 // 2 nodes per wave
  int spmm_blocks = (nwaves + 3) / 4;       // 4 waves per block
  constexpr int WPREP_TOTAL = DIN * HID + HID * HID + HID * DOUT;  // 57344
  int wblocks = (WPREP_TOTAL + 255) / 256;  // 224
  int iblocks = MAXB / 256;                 // 4

  initprep_kernel<<<iblocks + wblocks, 256, 0, stream>>>(
      bucket_total, iblocks,
      W1, W1hi, W1lo, W2, W2hi, W2lo, W3, W3hi, W3lo);
  bin_kernel<<<nbin, 256, 0, stream>>>(dst, e, nbuckets, bucket_total, block_base);
  scan_buckets_kernel<<<1, 256, 0, stream>>>(bucket_total, bucket_base, nbuckets);
  fusedA2_kernel<<<gemm_blocks + nbin, 256, 0, stream>>>(
      x, W1hi, W1lo, T, n, gemm_blocks,
      src, dst, bucket_base, block_base, binned, e, nbuckets);
  csr_kernel<<<nbuckets, 256, 0, stream>>>(binned, bucket_base, n, row_start, deg, dinv, col);

  spmm_kernel<HID, true, true><<<spmm_blocks, 256, 0, stream>>>(T, row_start, deg, col, dinv, b1, Hf, n);
  gemm_mfma_kernel<HID, HID><<<gemm_blocks, 256, 0, stream>>>(Hf, W2hi, W2lo, dinv, T, n);
  spmm_kernel<HID, true, false><<<spmm_blocks, 256, 0, stream>>>(T, row_start, deg, col, dinv, b2, Hf, n);
  gemm_mfma_kernel<HID, DOUT><<<gemm_blocks, 256, 0, stream>>>(Hf, W3hi, W3lo, dinv, T, n);
  spmm_kernel<DOUT, false, false><<<spmm_blocks, 256, 0, stream>>>(T, row_start, deg, col, dinv, b3, (float*)d_out, n);
}